// Round 22
// baseline (11199.309 us; speedup 1.0000x reference)
//
#include <hip/hip_runtime.h>
#include <hip/hip_bf16.h>

#define DEV static __device__ __forceinline__

typedef __attribute__((ext_vector_type(8))) short short8;
typedef __attribute__((ext_vector_type(4))) float f32x4;
#define MFMA16(a,b,c) __builtin_amdgcn_mfma_f32_16x16x32_bf16(a,b,c,0,0,0)

constexpr int Tc = 512;
constexpr int NB = 2048;              // 1 batch elem per block
constexpr int OUT_TR = 675840;
constexpr int OUT_AW = 677888;

// ---- d_ws bf16 frag-linear (u16 offsets) ----
constexpr unsigned WQKV = 0;          // l4 x hp4 x ks8 x ct12 x 512 (q-scale folded)
constexpr unsigned WO   = 786432;     // l4 x h8 x ct16 x 512   (K=32 per head)
constexpr unsigned WF1  = 1048576;    // l4 x ch4 x ks8 x ct16 x 512
constexpr unsigned WF2  = 2097152;    // l4 x ch4(k) x ks8 x ct16 x 512
constexpr unsigned WROT = 3145728;    // ch4 x ks8 x ct16 x 512
constexpr unsigned WP2  = 3407872;    // ks8 x ct16 x 512
constexpr unsigned WTOT = 3473408;

// ---- LDS (bytes): total 73216 -> 2 WGs/CU ----
constexpr int XBb   = 0;              // u16 [56][264]  29568
constexpr int AR    = 29568;          // arena 40960
constexpr int STATS = 70528;          // f32[128] mean|rstd
constexpr int CONDVb= 71040;          // f32[256]
constexpr int X55b  = 72064;          // f32[256]
constexpr int SMEM_TOT = 73216;

// u16 arena offsets
constexpr int ARu  = AR/2;            // 14784
constexpr int QPo  = ARu;             // [2][56][40]
constexpr int KPo  = ARu + 4480;
constexpr int VTo  = ARu + 8960;      // [2][32][72]
constexpr int SCBo = ARu + 13568;     // [56][72]
constexpr int OHo  = ARu + 17600;     // [56][40]
// f32 absolute indices
constexpr int PARTS_S  = 7392;        // [8][64]
constexpr int PARTS_S2 = 7904;
constexpr int PARTSGf  = 7392;
constexpr int VCSBf    = 7904;
constexpr int OCVf     = 8160;
constexpr int TRFf     = 7392;
constexpr int TMPFf    = 15072;
constexpr int BPFf     = 16224;
constexpr int STATSf   = 17632;
constexpr int WSUMf    = 17632;
constexpr int CONDVf   = 17760;
constexpr int X55f     = 18016;

struct FalseC { static constexpr bool value = false; };
struct TrueC  { static constexpr bool value = true;  };

struct PP {
  const float *sa_Wqkv,*sa_Wo,*ff_W1,*ff_W2,*rot_W1,*pose_W2;
  unsigned short* wb;
};
struct KP {
  const float *bp,*wrist,*betas;
  const float *pose_W1,*pose_b1,*pose_b2;
  const float *joints,*mask_emb,*transl_emb,*in_g,*in_b;
  const float *gender_tab,*cond_W1,*cond_b1,*cond_W2,*cond_b2,*cond_g,*cond_b;
  const float *rel_map;
  const float *sa_bqkv,*sa_bo;
  const float *ca_Wkv,*ca_bkv,*ca_Wo,*ca_bo;
  const float *ff_b1,*ff_b2;
  const float *ln1_g,*ln1_b,*ln2_g,*ln2_b,*ln3_g,*ln3_b;
  const float *rot_b1,*rot_W2,*rot_b2;
  const float *tr_W1,*tr_b1,*tr_W2,*tr_b2;
  const int *gender,*mask_ids;
  const unsigned short* wb;
  float* out;
};

DEV unsigned short f2b(float x){
  union { __hip_bfloat16 h; unsigned short u; } c; c.h = __float2bfloat16(x); return c.u;
}
DEV float b2f(unsigned short u){
  union { __hip_bfloat16 h; unsigned short u; } c; c.u = u; return __bfloat162float(c.h);
}
DEV float gelu_f(float x){
  float z = 0.7978845608028654f * (x + 0.044715f * x * x * x);
  return x / (1.0f + __expf(-2.0f * z));
}
DEV float wred_sum(float v){
  #pragma unroll
  for (int m = 32; m; m >>= 1) v += __shfl_xor(v, m, 64);
  return v;
}
DEV float wred_max(float v){
  #pragma unroll
  for (int m = 32; m; m >>= 1) v = fmaxf(v, __shfl_xor(v, m, 64));
  return v;
}

// ================= prep =================
__global__ __launch_bounds__(256)
void prep_kernel(PP a){
  unsigned i = blockIdx.x*256u + threadIdx.x;
  if (i >= WTOT) return;
  float v;
  if (i < WO){                                   // WQKV
    unsigned l=i/196608u, r=i%196608u, hp=r/49152u, r2=r%49152u;
    unsigned ks=r2/6144u, r3=r2%6144u, ct=r3/512u, r4=r3&511u;
    unsigned lane=r4>>3, e=r4&7u;
    unsigned c192=ct*16u+(lane&15u), k=ks*32u+((lane>>4)<<3)+e;
    unsigned part=c192>>6, hh=(c192>>5)&1u, d=c192&31u;
    v = a.sa_Wqkv[l*196608u + k*768u + part*256u + (hp*2u+hh)*32u + d];
    if (part==0u) v *= 0.17677669529663687f;
  } else if (i < WF1){                           // WO per-head K=32
    unsigned j=i-WO, l=j/65536u, r=j%65536u, h=r/8192u, r2=r%8192u;
    unsigned ct=r2/512u, r4=r2&511u, lane=r4>>3, e=r4&7u;
    unsigned col=ct*16u+(lane&15u), k=((lane>>4)<<3)+e;
    v = a.sa_Wo[l*65536u + (h*32u+k)*256u + col];
  } else if (i < WF2){                           // WF1
    unsigned j=i-WF1, l=j/262144u, r=j%262144u, ch=r/65536u, r2=r%65536u;
    unsigned ks=r2/8192u, r3=r2%8192u, ct=r3/512u, r4=r3&511u, lane=r4>>3, e=r4&7u;
    unsigned col=ct*16u+(lane&15u), k=ks*32u+((lane>>4)<<3)+e;
    v = a.ff_W1[l*262144u + k*1024u + ch*256u + col];
  } else if (i < WROT){                          // WF2
    unsigned j=i-WF2, l=j/262144u, r=j%262144u, ch=r/65536u, r2=r%65536u;
    unsigned ks=r2/8192u, r3=r2%8192u, ct=r3/512u, r4=r3&511u, lane=r4>>3, e=r4&7u;
    unsigned col=ct*16u+(lane&15u), k=ks*32u+((lane>>4)<<3)+e;
    v = a.ff_W2[l*262144u + (ch*256u+k)*256u + col];
  } else if (i < WP2){                           // WROT
    unsigned j=i-WROT, ch=j/65536u, r2=j%65536u;
    unsigned ks=r2/8192u, r3=r2%8192u, ct=r3/512u, r4=r3&511u, lane=r4>>3, e=r4&7u;
    unsigned col=ct*16u+(lane&15u), k=ks*32u+((lane>>4)<<3)+e;
    v = a.rot_W1[k*1024u + ch*256u + col];
  } else {                                       // WP2
    unsigned j=i-WP2, ks=j/8192u, r3=j%8192u;
    unsigned ct=r3/512u, r4=r3&511u, lane=r4>>3, e=r4&7u;
    unsigned col=ct*16u+(lane&15u), k=ks*32u+((lane>>4)<<3)+e;
    v = a.pose_W2[k*256u + col];
  }
  a.wb[i] = f2b(v);
}

// ================= helpers =================
// E=1 GEMM, NO software prefetch (r21 best form): loads inside a non-unrolled
// loop; 16 live B regs; #pragma unroll 1 stops load hoisting (r17 CSE lesson).
DEV void gemmE1(const unsigned short* su, int ao, int astr,
                const unsigned short* Bg, int ct0, int ct1, int nct,
                f32x4* C0, f32x4* C1, int lane){
  const unsigned short* A  = su + ao + (lane & 15)*astr + ((lane >> 4) << 3);
  const unsigned short* B0 = Bg + (size_t)ct0*512 + lane*8;
  const unsigned short* B1 = Bg + (size_t)ct1*512 + lane*8;
  const int step = nct*512;
  #pragma unroll 1
  for (int ks = 0; ks < 8; ++ks){
    short8 b0 = *(const short8*)(B0);
    short8 b1 = *(const short8*)(B1);
    #pragma unroll
    for (int m = 0; m < 4; ++m){
      short8 a = *(const short8*)(A + m*16*astr);
      C0[m] = MFMA16(a, b0, C0[m]);
      C1[m] = MFMA16(a, b1, C1[m]);
    }
    A += 32; B0 += step; B1 += step;
  }
}

__global__ __launch_bounds__(Tc, 4)
void actor_kernel(KP p){
  __shared__ __align__(16) char smem[SMEM_TOT];
  float* sf = (float*)smem;
  unsigned short* su = (unsigned short*)smem;

  const int t = threadIdx.x;
  const int lane = t & 63, wv = t >> 6;   // 8 waves
  const int hi = lane >> 4;
  const int col0 = wv*32 + (lane & 15), col1 = col0 + 16;
  const int b = blockIdx.x;
  const f32x4 fz = {0.f,0.f,0.f,0.f};

  f32x4 xsr[2][4];
  float awr[7] = {0,0,0,0,0,0,0};   // only referenced in layer-3 instantiation

  auto ln_regs = [&](const float* g, const float* bta, bool wxb){
    #pragma unroll
    for (int m = 0; m < 4; ++m){
      #pragma unroll
      for (int j = 0; j < 4; ++j){
        float v0 = xsr[0][m][j], v1 = xsr[1][m][j];
        float s = v0 + v1, s2 = v0*v0 + v1*v1;
        #pragma unroll
        for (int mk = 1; mk < 16; mk <<= 1){
          s += __shfl_xor(s, mk, 64); s2 += __shfl_xor(s2, mk, 64);
        }
        if ((lane & 15) == 0){
          int row = m*16 + hi*4 + j;
          sf[PARTS_S  + wv*64 + row] = s;
          sf[PARTS_S2 + wv*64 + row] = s2;
        }
      }
    }
    __syncthreads();
    if (t < 64){
      float s = 0.f, s2 = 0.f;
      #pragma unroll
      for (int w = 0; w < 8; ++w){
        s  += sf[PARTS_S  + w*64 + t];
        s2 += sf[PARTS_S2 + w*64 + t];
      }
      float mean = s * (1.f/256.f);
      float var  = s2 * (1.f/256.f) - mean*mean;
      sf[STATSf + t]      = mean;
      sf[STATSf + 64 + t] = rsqrtf(var + 1e-5f);
    }
    __syncthreads();
    float g0 = g[col0], bb0 = bta[col0], g1 = g[col1], bb1 = bta[col1];
    #pragma unroll
    for (int m = 0; m < 4; ++m){
      #pragma unroll
      for (int j = 0; j < 4; ++j){
        int row = m*16 + hi*4 + j;
        float mean = sf[STATSf + row], rstd = sf[STATSf + 64 + row];
        float o0 = (xsr[0][m][j] - mean)*rstd*g0 + bb0;
        float o1 = (xsr[1][m][j] - mean)*rstd*g1 + bb1;
        xsr[0][m][j] = o0; xsr[1][m][j] = o1;
        if (wxb && row < 56){
          su[XBb/2 + row*264 + col0] = f2b(o0);
          su[XBb/2 + row*264 + col1] = f2b(o1);
        }
      }
    }
    if (wxb) __syncthreads();
  };

  // ================= prologue =================
  if (t < 29){
    float v;
    if (t < 10) v = p.wrist[b*10 + t];
    else if (t < 13) v = p.betas[b*3 + (t-10)];
    else { int g = p.gender[b]; v = p.gender_tab[g*16 + (t-13)]; }
    sf[X55f + t] = v;
  }
  if (t < 330) sf[BPFf + t] = p.bp[(size_t)b*330 + t];
  __syncthreads();
  {
    float a = p.cond_b1[t];
    #pragma unroll 1
    for (int k = 0; k < 29; ++k) a = fmaf(sf[X55f + k], p.cond_W1[k*512 + t], a);
    sf[TMPFf + t] = gelu_f(a);
  }
  __syncthreads();
  {
    int c = t & 255, pg = t >> 8;
    float a = 0.f;
    for (int k = pg*256; k < pg*256 + 256; ++k)
      a = fmaf(sf[TMPFf + k], p.cond_W2[(size_t)k*256 + c], a);
    sf[PARTSGf + pg*256 + c] = a;
  }
  __syncthreads();
  if (t < 256) sf[CONDVf + t] = p.cond_b2[t] + sf[PARTSGf + t] + sf[PARTSGf + 256 + t];
  __syncthreads();
  if (wv == 0){
    float v[4], s = 0.f, s2 = 0.f;
    #pragma unroll
    for (int u = 0; u < 4; ++u){ v[u] = sf[CONDVf + lane + 64*u]; s += v[u]; s2 = fmaf(v[u], v[u], s2); }
    s = wred_sum(s); s2 = wred_sum(s2);
    float mean = s * (1.f/256.f);
    float var  = s2 * (1.f/256.f) - mean*mean;
    float rs = rsqrtf(var + 1e-5f);
    #pragma unroll
    for (int u = 0; u < 4; ++u){
      int n = lane + 64*u;
      sf[CONDVf + n] = (v[u]-mean)*rs*p.cond_g[n] + p.cond_b[n];
    }
  }
  {
    int n = t & 255, mb = t >> 8;
    for (int m = mb; m < 55; m += 2){
      float a = p.pose_b1[n];
      #pragma unroll
      for (int k = 0; k < 6; ++k) a = fmaf(sf[BPFf + m*6 + k], p.pose_W1[k*256 + n], a);
      su[ARu + m*264 + n] = f2b(gelu_f(a));
    }
    if (t < 256) su[ARu + 55*264 + t] = 0;
  }
  __syncthreads();
  {
    f32x4 e0[4] = {fz,fz,fz,fz}, e1[4] = {fz,fz,fz,fz};
    gemmE1(su, ARu, 264, p.wb + WP2, 2*wv, 2*wv+1, 16, e0, e1, lane);
    #pragma unroll
    for (int c = 0; c < 2; ++c){
      f32x4* ac = c ? e1 : e0;
      int colc = c ? col1 : col0;
      #pragma unroll
      for (int m = 0; m < 4; ++m){
        #pragma unroll
        for (int j = 0; j < 4; ++j){
          int row = m*16 + hi*4 + j;
          float v = 0.f;
          if (row < 56){
            v = (row < 55) ? (ac[m][j] + p.pose_b2[colc]) : p.transl_emb[colc];
            v = p.mask_ids[b*56 + row] ? v : p.mask_emb[colc];
            v += p.joints[row*256 + colc];
          }
          xsr[c][m][j] = v;
        }
      }
    }
  }
  __syncthreads();
  ln_regs(p.in_g, p.in_b, true);

  // ================= layer body (templated on LAST to confine awr) =========
  auto layer_body = [&](int l, auto lastc){
    constexpr bool LAST = decltype(lastc)::value;
    const float* bqkv = p.sa_bqkv + l*768;

    for (int hp = 0; hp < 4; ++hp){
      su[VTo + (t>>8)*2304 + ((t>>3)&31)*72 + 56 + (t&7)] = 0;
      {
        int ctA = (wv < 4) ? 2*wv : wv + 4;
        int ctB = (wv < 4) ? 2*wv + 1 : ctA;
        f32x4 qA[4] = {fz,fz,fz,fz}, qB[4] = {fz,fz,fz,fz};
        gemmE1(su, XBb/2, 264, p.wb + WQKV + (size_t)(l*4 + hp)*49152, ctA, ctB, 12, qA, qB, lane);
        #pragma unroll
        for (int c = 0; c < 2; ++c){
          if (c == 1 && wv >= 4) break;
          f32x4* ac = c ? qB : qA;
          int ct = c ? ctB : ctA;
          int c192 = ct*16 + (lane & 15);
          int part = c192 >> 6, hh2 = (c192 >> 5) & 1, d = c192 & 31;
          float bias = bqkv[part*256 + (hp*2 + hh2)*32 + d];
          if (part == 0) bias *= 0.17677669529663687f;
          #pragma unroll
          for (int m = 0; m < 4; ++m){
            #pragma unroll
            for (int j = 0; j < 4; ++j){
              int row = m*16 + hi*4 + j;
              if (row < 56){
                float v = ac[m][j] + bias;
                if (part == 0)      su[QPo + hh2*2240 + row*40 + d] = f2b(v);
                else if (part == 1) su[KPo + hh2*2240 + row*40 + d] = f2b(v);
                else                su[VTo + hh2*2304 + d*72 + row] = f2b(v);
              }
            }
          }
        }
      }
      __syncthreads();

      for (int hh = 0; hh < 2; ++hh){
        {
          int m = wv >> 1;
          short8 a = *(const short8*)(su + QPo + hh*2240 + (m*16 + (lane&15))*40 + (hi<<3));
          #pragma unroll
          for (int i = 0; i < 2; ++i){
            int n = (wv & 1)*2 + i;
            short8 bf_ = *(const short8*)(su + KPo + hh*2240 + (n*16 + (lane&15))*40 + (hi<<3));
            f32x4 d = MFMA16(a, bf_, fz);
            #pragma unroll
            for (int j = 0; j < 4; ++j){
              int row = m*16 + hi*4 + j, key = n*16 + (lane & 15);
              if (row < 56 && key < 56)
                su[SCBo + row*72 + key] = f2b(d[j] + p.rel_map[row*56 + key]);
            }
          }
        }
        __syncthreads();
        #pragma unroll
        for (int q = 0; q < 7; ++q){
          int r = wv*7 + q;
          float v = (lane < 56) ? b2f(su[SCBo + r*72 + lane]) : -3.0e38f;
          float mx = wred_max(v);
          float ex = (lane < 56) ? __expf(v - mx) : 0.f;
          float s = wred_sum(ex);
          float a = ex / s;
          su[SCBo + r*72 + lane] = (lane < 56) ? f2b(a) : (unsigned short)0;
          if constexpr (LAST) awr[q] += a * 0.125f;
        }
        __syncthreads();
        {
          int m = wv >> 1, dt = wv & 1;
          f32x4 o = fz;
          #pragma unroll
          for (int ks = 0; ks < 2; ++ks){
            short8 a  = *(const short8*)(su + SCBo + (m*16 + (lane&15))*72 + ks*32 + (hi<<3));
            short8 bf_= *(const short8*)(su + VTo + hh*2304 + (dt*16 + (lane&15))*72 + ks*32 + (hi<<3));
            o = MFMA16(a, bf_, o);
          }
          #pragma unroll
          for (int j = 0; j < 4; ++j){
            int row = m*16 + hi*4 + j;
            if (row < 56) su[OHo + row*40 + dt*16 + (lane & 15)] = f2b(o[j]);
          }
        }
        __syncthreads();
        {
          const unsigned short* Bg = p.wb + WO + (size_t)(l*8 + hp*2 + hh)*8192;
          short8 w0 = *(const short8*)(Bg + (size_t)(2*wv)*512 + lane*8);
          short8 w1 = *(const short8*)(Bg + (size_t)(2*wv+1)*512 + lane*8);
          #pragma unroll
          for (int m = 0; m < 4; ++m){
            short8 a = *(const short8*)(su + OHo + (m*16 + (lane&15))*40 + (hi<<3));
            xsr[0][m] = MFMA16(a, w0, xsr[0][m]);
            xsr[1][m] = MFMA16(a, w1, xsr[1][m]);
          }
        }
        __syncthreads();
      }
    } // head pairs

    {
      float bo0 = p.sa_bo[l*256 + col0], bo1 = p.sa_bo[l*256 + col1];
      #pragma unroll
      for (int m = 0; m < 4; ++m)
        #pragma unroll
        for (int j = 0; j < 4; ++j){ xsr[0][m][j] += bo0; xsr[1][m][j] += bo1; }
    }
    ln_regs(p.ln1_g + l*256, p.ln1_b + l*256, false);

    {
      int c = t & 255, pg = t >> 8;
      float a = 0.f;
      const float* W = p.ca_Wkv + (size_t)l*131072 + 256 + c;
      for (int k = pg*128; k < pg*128 + 128; ++k) a = fmaf(sf[CONDVf + k], W[(size_t)k*512], a);
      sf[PARTSGf + pg*256 + c] = a;
    }
    __syncthreads();
    if (t < 256) sf[VCSBf + t] = p.ca_bkv[l*512 + 256 + t] + sf[PARTSGf + t] + sf[PARTSGf + 256 + t];
    __syncthreads();
    {
      int c = t & 255, pg = t >> 8;
      float a = 0.f;
      const float* W = p.ca_Wo + (size_t)l*65536 + c;
      for (int k = pg*128; k < pg*128 + 128; ++k) a = fmaf(sf[VCSBf + k], W[(size_t)k*256], a);
      sf[PARTSGf + pg*256 + c] = a;
    }
    __syncthreads();
    if (t < 256) sf[OCVf + t] = p.ca_bo[l*256 + t] + sf[PARTSGf + t] + sf[PARTSGf + 256 + t];
    __syncthreads();
    {
      float o0 = sf[OCVf + col0], o1 = sf[OCVf + col1];
      #pragma unroll
      for (int m = 0; m < 4; ++m)
        #pragma unroll
        for (int j = 0; j < 4; ++j){ xsr[0][m][j] += o0; xsr[1][m][j] += o1; }
    }
    __syncthreads();
    ln_regs(p.ln2_g + l*256, p.ln2_b + l*256, true);

    for (int ch = 0; ch < 4; ++ch){
      f32x4 f0[4] = {fz,fz,fz,fz}, f1[4] = {fz,fz,fz,fz};
      gemmE1(su, XBb/2, 264, p.wb + WF1 + (size_t)(l*4 + ch)*65536, 2*wv, 2*wv+1, 16, f0, f1, lane);
      const float* b1 = p.ff_b1 + l*1024 + ch*256;
      #pragma unroll
      for (int c = 0; c < 2; ++c){
        f32x4* fc = c ? f1 : f0;
        int colc = c ? col1 : col0;
        #pragma unroll
        for (int m = 0; m < 4; ++m){
          #pragma unroll
          for (int j = 0; j < 4; ++j){
            int row = m*16 + hi*4 + j;
            if (row < 56) su[ARu + row*264 + colc] = f2b(gelu_f(fc[m][j] + b1[colc]));
          }
        }
      }
      __syncthreads();
      gemmE1(su, ARu, 264, p.wb + WF2 + (size_t)(l*4 + ch)*65536, 2*wv, 2*wv+1, 16, xsr[0], xsr[1], lane);
      __syncthreads();
    }
    {
      float bo0 = p.ff_b2[l*256 + col0], bo1 = p.ff_b2[l*256 + col1];
      #pragma unroll
      for (int m = 0; m < 4; ++m)
        #pragma unroll
        for (int j = 0; j < 4; ++j){ xsr[0][m][j] += bo0; xsr[1][m][j] += bo1; }
    }
    ln_regs(p.ln3_g + l*256, p.ln3_b + l*256, true);
  };

  // layers 0-2 without awr; layer 3 with awr (peeled)
  #pragma unroll 1
  for (int l = 0; l < 3; ++l) layer_body(l, FalseC{});
  layer_body(3, TrueC{});

  // ---- attn_w out ----
  if (lane < 56){
    #pragma unroll
    for (int q = 0; q < 7; ++q)
      p.out[OUT_AW + (size_t)b*3136 + (wv*7 + q)*56 + lane] = awr[q];
  }
  if (hi == 1){
    sf[X55f + col0] = xsr[0][3][3];
    sf[X55f + col1] = xsr[1][3][3];
  }

  // ---- pose head ----
  {
    float pacc = 0.f;
    int mp = t / 6, op = t - mp*6;
    for (int ch = 0; ch < 4; ++ch){
      f32x4 r0[4] = {fz,fz,fz,fz}, r1[4] = {fz,fz,fz,fz};
      gemmE1(su, XBb/2, 264, p.wb + WROT + (size_t)ch*65536, 2*wv, 2*wv+1, 16, r0, r1, lane);
      const float* rb = p.rot_b1 + ch*256;
      #pragma unroll
      for (int c = 0; c < 2; ++c){
        f32x4* rc = c ? r1 : r0;
        int colc = c ? col1 : col0;
        #pragma unroll
        for (int m = 0; m < 4; ++m){
          #pragma unroll
          for (int j = 0; j < 4; ++j){
            int row = m*16 + hi*4 + j;
            if (row < 56) su[ARu + row*264 + colc] = f2b(gelu_f(rc[m][j] + rb[colc]));
          }
        }
      }
      __syncthreads();
      if (t < 330){
        for (int d = 0; d < 256; ++d)
          pacc = fmaf(b2f(su[ARu + mp*264 + d]), p.rot_W2[(size_t)(ch*256 + d)*6 + op], pacc);
      }
      __syncthreads();
    }
    if (t < 330) p.out[(size_t)b*330 + t] = pacc + p.rot_b2[op];
  }

  // ---- transl head ----
  {
    #pragma unroll
    for (int hf = 0; hf < 2; ++hf){
      int c = t + hf*512;
      float a = p.tr_b1[c];
      for (int k = 0; k < 256; ++k) a = fmaf(sf[X55f + k], p.tr_W1[(size_t)k*1024 + c], a);
      sf[TRFf + c] = gelu_f(a);
    }
    __syncthreads();
    float part = 0.f;
    #pragma unroll
    for (int hf = 0; hf < 2; ++hf){
      int c = t + hf*512;
      part = fmaf(sf[TRFf + c], p.tr_W2[c], part);
    }
    part = wred_sum(part);
    if (lane == 0) sf[WSUMf + wv] = part;
    __syncthreads();
    if (t == 0){
      float s = p.tr_b2[0];
      #pragma unroll
      for (int w = 0; w < 8; ++w) s += sf[WSUMf + w];
      p.out[OUT_TR + b] = s;
    }
  }
}

extern "C" void kernel_launch(void* const* d_in, const int* in_sizes, int n_in,
                              void* d_out, int out_size, void* d_ws, size_t ws_size,
                              hipStream_t stream){
  (void)in_sizes; (void)n_in; (void)out_size; (void)ws_size;
  auto F = [&](int i) -> const float* { return (const float*)d_in[i]; };

  PP pp;
  pp.sa_Wqkv = F(20); pp.sa_Wo = F(22); pp.ff_W1 = F(30); pp.ff_W2 = F(32);
  pp.rot_W1 = F(40); pp.pose_W2 = F(5);
  pp.wb = (unsigned short*)d_ws;
  hipLaunchKernelGGL(prep_kernel, dim3((WTOT + 255u)/256u), dim3(256), 0, stream, pp);

  KP p;
  p.bp = F(0); p.wrist = F(1); p.betas = F(2);
  p.pose_W1 = F(3); p.pose_b1 = F(4); p.pose_b2 = F(6);
  p.joints = F(7); p.mask_emb = F(8); p.transl_emb = F(9);
  p.in_g = F(10); p.in_b = F(11);
  p.gender_tab = F(12);
  p.cond_W1 = F(13); p.cond_b1 = F(14); p.cond_W2 = F(15); p.cond_b2 = F(16);
  p.cond_g = F(17); p.cond_b = F(18);
  p.rel_map = F(19);
  p.sa_bqkv = F(21); p.sa_bo = F(23);
  p.ca_Wkv = F(26); p.ca_bkv = F(27); p.ca_Wo = F(28); p.ca_bo = F(29);
  p.ff_b1 = F(31); p.ff_b2 = F(33);
  p.ln1_g = F(34); p.ln1_b = F(35); p.ln2_g = F(36); p.ln2_b = F(37);
  p.ln3_g = F(38); p.ln3_b = F(39);
  p.rot_b1 = F(41); p.rot_W2 = F(42); p.rot_b2 = F(43);
  p.tr_W1 = F(44); p.tr_b1 = F(45); p.tr_W2 = F(46); p.tr_b2 = F(47);
  p.gender = (const int*)d_in[48]; p.mask_ids = (const int*)d_in[49];
  p.wb = (const unsigned short*)d_ws;
  p.out = (float*)d_out;

  hipLaunchKernelGGL(actor_kernel, dim3(NB), dim3(Tc), 0, stream, p);
}

// Round 23
// 4405.085 us; speedup vs baseline: 2.5424x; 2.5424x over previous
//
#include <hip/hip_runtime.h>
#include <hip/hip_bf16.h>

#define DEV static __device__ __forceinline__

typedef __attribute__((ext_vector_type(8))) short short8;
typedef __attribute__((ext_vector_type(4))) float f32x4;
#define MFMA16(a,b,c) __builtin_amdgcn_mfma_f32_16x16x32_bf16(a,b,c,0,0,0)

constexpr int Tc = 512;
constexpr int NB = 2048;              // 1 batch elem per block
constexpr int OUT_TR = 675840;
constexpr int OUT_AW = 677888;

// ---- d_ws bf16 frag-linear (u16 offsets) ----
constexpr unsigned WQKV = 0;          // l4 x hp4 x ks8 x ct12 x 512 (q-scale folded)
constexpr unsigned WO   = 786432;     // l4 x h8 x ct16 x 512   (K=32 per head)
constexpr unsigned WF1  = 1048576;    // l4 x ch4 x ks8 x ct16 x 512
constexpr unsigned WF2  = 2097152;    // l4 x ch4(k) x ks8 x ct16 x 512
constexpr unsigned WROT = 3145728;    // ch4 x ks8 x ct16 x 512
constexpr unsigned WP2  = 3407872;    // ks8 x ct16 x 512
constexpr unsigned WTOT = 3473408;

// ---- LDS (bytes): total 73216 -> 2 WGs/CU ----
constexpr int XBb   = 0;              // u16 [56][264]  29568
constexpr int AR    = 29568;          // arena 40960
constexpr int STATS = 70528;          // f32[128] mean|rstd
constexpr int CONDVb= 71040;          // f32[256]
constexpr int X55b  = 72064;          // f32[256]
constexpr int SMEM_TOT = 73216;

// u16 arena offsets
constexpr int ARu  = AR/2;            // 14784
constexpr int QPo  = ARu;             // [2][56][40]
constexpr int KPo  = ARu + 4480;
constexpr int VTo  = ARu + 8960;      // [2][32][72]
constexpr int SCBo = ARu + 13568;     // [56][72]
constexpr int OHo  = ARu + 17600;     // [56][40]
// f32 absolute indices
constexpr int PARTS_S  = 7392;        // [8][64]
constexpr int PARTS_S2 = 7904;
constexpr int PARTSGf  = 7392;
constexpr int VCSBf    = 7904;
constexpr int OCVf     = 8160;
constexpr int TRFf     = 7392;
constexpr int TMPFf    = 15072;
constexpr int BPFf     = 16224;
constexpr int STATSf   = 17632;
constexpr int WSUMf    = 17632;
constexpr int CONDVf   = 17760;
constexpr int X55f     = 18016;

struct PP {
  const float *sa_Wqkv,*sa_Wo,*ff_W1,*ff_W2,*rot_W1,*pose_W2;
  unsigned short* wb;
};
struct KP {
  const float *bp,*wrist,*betas;
  const float *pose_W1,*pose_b1,*pose_b2;
  const float *joints,*mask_emb,*transl_emb,*in_g,*in_b;
  const float *gender_tab,*cond_W1,*cond_b1,*cond_W2,*cond_b2,*cond_g,*cond_b;
  const float *rel_map;
  const float *sa_bqkv,*sa_bo;
  const float *ca_Wkv,*ca_bkv,*ca_Wo,*ca_bo;
  const float *ff_b1,*ff_b2;
  const float *ln1_g,*ln1_b,*ln2_g,*ln2_b,*ln3_g,*ln3_b;
  const float *rot_b1,*rot_W2,*rot_b2;
  const float *tr_W1,*tr_b1,*tr_W2,*tr_b2;
  const int *gender,*mask_ids;
  const unsigned short* wb;
  float* out;
};

DEV unsigned short f2b(float x){
  union { __hip_bfloat16 h; unsigned short u; } c; c.h = __float2bfloat16(x); return c.u;
}
DEV float b2f(unsigned short u){
  union { __hip_bfloat16 h; unsigned short u; } c; c.u = u; return __bfloat162float(c.h);
}
DEV float gelu_f(float x){
  float z = 0.7978845608028654f * (x + 0.044715f * x * x * x);
  return x / (1.0f + __expf(-2.0f * z));
}
DEV float wred_sum(float v){
  #pragma unroll
  for (int m = 32; m; m >>= 1) v += __shfl_xor(v, m, 64);
  return v;
}
DEV float wred_max(float v){
  #pragma unroll
  for (int m = 32; m; m >>= 1) v = fmaxf(v, __shfl_xor(v, m, 64));
  return v;
}

// ================= prep =================
__global__ __launch_bounds__(256)
void prep_kernel(PP a){
  unsigned i = blockIdx.x*256u + threadIdx.x;
  if (i >= WTOT) return;
  float v;
  if (i < WO){                                   // WQKV
    unsigned l=i/196608u, r=i%196608u, hp=r/49152u, r2=r%49152u;
    unsigned ks=r2/6144u, r3=r2%6144u, ct=r3/512u, r4=r3&511u;
    unsigned lane=r4>>3, e=r4&7u;
    unsigned c192=ct*16u+(lane&15u), k=ks*32u+((lane>>4)<<3)+e;
    unsigned part=c192>>6, hh=(c192>>5)&1u, d=c192&31u;
    v = a.sa_Wqkv[l*196608u + k*768u + part*256u + (hp*2u+hh)*32u + d];
    if (part==0u) v *= 0.17677669529663687f;
  } else if (i < WF1){                           // WO per-head K=32
    unsigned j=i-WO, l=j/65536u, r=j%65536u, h=r/8192u, r2=r%8192u;
    unsigned ct=r2/512u, r4=r2&511u, lane=r4>>3, e=r4&7u;
    unsigned col=ct*16u+(lane&15u), k=((lane>>4)<<3)+e;
    v = a.sa_Wo[l*65536u + (h*32u+k)*256u + col];
  } else if (i < WF2){                           // WF1
    unsigned j=i-WF1, l=j/262144u, r=j%262144u, ch=r/65536u, r2=r%65536u;
    unsigned ks=r2/8192u, r3=r2%8192u, ct=r3/512u, r4=r3&511u, lane=r4>>3, e=r4&7u;
    unsigned col=ct*16u+(lane&15u), k=ks*32u+((lane>>4)<<3)+e;
    v = a.ff_W1[l*262144u + k*1024u + ch*256u + col];
  } else if (i < WROT){                          // WF2
    unsigned j=i-WF2, l=j/262144u, r=j%262144u, ch=r/65536u, r2=r%65536u;
    unsigned ks=r2/8192u, r3=r2%8192u, ct=r3/512u, r4=r3&511u, lane=r4>>3, e=r4&7u;
    unsigned col=ct*16u+(lane&15u), k=ks*32u+((lane>>4)<<3)+e;
    v = a.ff_W2[l*262144u + (ch*256u+k)*256u + col];
  } else if (i < WP2){                           // WROT
    unsigned j=i-WROT, ch=j/65536u, r2=j%65536u;
    unsigned ks=r2/8192u, r3=r2%8192u, ct=r3/512u, r4=r3&511u, lane=r4>>3, e=r4&7u;
    unsigned col=ct*16u+(lane&15u), k=ks*32u+((lane>>4)<<3)+e;
    v = a.rot_W1[k*1024u + ch*256u + col];
  } else {                                       // WP2
    unsigned j=i-WP2, ks=j/8192u, r3=j%8192u;
    unsigned ct=r3/512u, r4=r3&511u, lane=r4>>3, e=r4&7u;
    unsigned col=ct*16u+(lane&15u), k=ks*32u+((lane>>4)<<3)+e;
    v = a.pose_W2[k*256u + col];
  }
  a.wb[i] = f2b(v);
}

// ================= helpers =================
// E=1 GEMM, NO software prefetch (r21 best form): loads inside a non-unrolled
// loop; 16 live B regs; #pragma unroll 1 stops load hoisting (r17 CSE lesson).
DEV void gemmE1(const unsigned short* su, int ao, int astr,
                const unsigned short* Bg, int ct0, int ct1, int nct,
                f32x4* C0, f32x4* C1, int lane){
  const unsigned short* A  = su + ao + (lane & 15)*astr + ((lane >> 4) << 3);
  const unsigned short* B0 = Bg + (size_t)ct0*512 + lane*8;
  const unsigned short* B1 = Bg + (size_t)ct1*512 + lane*8;
  const int step = nct*512;
  #pragma unroll 1
  for (int ks = 0; ks < 8; ++ks){
    short8 b0 = *(const short8*)(B0);
    short8 b1 = *(const short8*)(B1);
    #pragma unroll
    for (int m = 0; m < 4; ++m){
      short8 a = *(const short8*)(A + m*16*astr);
      C0[m] = MFMA16(a, b0, C0[m]);
      C1[m] = MFMA16(a, b1, C1[m]);
    }
    A += 32; B0 += step; B1 += step;
  }
}

__global__ __launch_bounds__(Tc, 4)
void actor_kernel(KP p){
  __shared__ __align__(16) char smem[SMEM_TOT];
  float* sf = (float*)smem;
  unsigned short* su = (unsigned short*)smem;

  const int t = threadIdx.x;
  const int lane = t & 63, wv = t >> 6;   // 8 waves
  const int hi = lane >> 4;
  const int col0 = wv*32 + (lane & 15), col1 = col0 + 16;
  const int b = blockIdx.x;
  const f32x4 fz = {0.f,0.f,0.f,0.f};

  f32x4 xsr[2][4];
  float awr[7] = {0,0,0,0,0,0,0};

  auto ln_regs = [&](const float* g, const float* bta, bool wxb){
    #pragma unroll
    for (int m = 0; m < 4; ++m){
      #pragma unroll
      for (int j = 0; j < 4; ++j){
        float v0 = xsr[0][m][j], v1 = xsr[1][m][j];
        float s = v0 + v1, s2 = v0*v0 + v1*v1;
        #pragma unroll
        for (int mk = 1; mk < 16; mk <<= 1){
          s += __shfl_xor(s, mk, 64); s2 += __shfl_xor(s2, mk, 64);
        }
        if ((lane & 15) == 0){
          int row = m*16 + hi*4 + j;
          sf[PARTS_S  + wv*64 + row] = s;
          sf[PARTS_S2 + wv*64 + row] = s2;
        }
      }
    }
    __syncthreads();
    if (t < 64){
      float s = 0.f, s2 = 0.f;
      #pragma unroll
      for (int w = 0; w < 8; ++w){
        s  += sf[PARTS_S  + w*64 + t];
        s2 += sf[PARTS_S2 + w*64 + t];
      }
      float mean = s * (1.f/256.f);
      float var  = s2 * (1.f/256.f) - mean*mean;
      sf[STATSf + t]      = mean;
      sf[STATSf + 64 + t] = rsqrtf(var + 1e-5f);
    }
    __syncthreads();
    float g0 = g[col0], bb0 = bta[col0], g1 = g[col1], bb1 = bta[col1];
    #pragma unroll
    for (int m = 0; m < 4; ++m){
      #pragma unroll
      for (int j = 0; j < 4; ++j){
        int row = m*16 + hi*4 + j;
        float mean = sf[STATSf + row], rstd = sf[STATSf + 64 + row];
        float o0 = (xsr[0][m][j] - mean)*rstd*g0 + bb0;
        float o1 = (xsr[1][m][j] - mean)*rstd*g1 + bb1;
        xsr[0][m][j] = o0; xsr[1][m][j] = o1;
        if (wxb && row < 56){
          su[XBb/2 + row*264 + col0] = f2b(o0);
          su[XBb/2 + row*264 + col1] = f2b(o1);
        }
      }
    }
    if (wxb) __syncthreads();
  };

  // ================= prologue =================
  if (t < 29){
    float v;
    if (t < 10) v = p.wrist[b*10 + t];
    else if (t < 13) v = p.betas[b*3 + (t-10)];
    else { int g = p.gender[b]; v = p.gender_tab[g*16 + (t-13)]; }
    sf[X55f + t] = v;
  }
  if (t < 330) sf[BPFf + t] = p.bp[(size_t)b*330 + t];
  __syncthreads();
  {
    float a = p.cond_b1[t];
    #pragma unroll 1
    for (int k = 0; k < 29; ++k) a = fmaf(sf[X55f + k], p.cond_W1[k*512 + t], a);
    sf[TMPFf + t] = gelu_f(a);
  }
  __syncthreads();
  {
    int c = t & 255, pg = t >> 8;
    float a = 0.f;
    for (int k = pg*256; k < pg*256 + 256; ++k)
      a = fmaf(sf[TMPFf + k], p.cond_W2[(size_t)k*256 + c], a);
    sf[PARTSGf + pg*256 + c] = a;
  }
  __syncthreads();
  if (t < 256) sf[CONDVf + t] = p.cond_b2[t] + sf[PARTSGf + t] + sf[PARTSGf + 256 + t];
  __syncthreads();
  if (wv == 0){
    float v[4], s = 0.f, s2 = 0.f;
    #pragma unroll
    for (int u = 0; u < 4; ++u){ v[u] = sf[CONDVf + lane + 64*u]; s += v[u]; s2 = fmaf(v[u], v[u], s2); }
    s = wred_sum(s); s2 = wred_sum(s2);
    float mean = s * (1.f/256.f);
    float var  = s2 * (1.f/256.f) - mean*mean;
    float rs = rsqrtf(var + 1e-5f);
    #pragma unroll
    for (int u = 0; u < 4; ++u){
      int n = lane + 64*u;
      sf[CONDVf + n] = (v[u]-mean)*rs*p.cond_g[n] + p.cond_b[n];
    }
  }
  {
    int n = t & 255, mb = t >> 8;
    for (int m = mb; m < 55; m += 2){
      float a = p.pose_b1[n];
      #pragma unroll
      for (int k = 0; k < 6; ++k) a = fmaf(sf[BPFf + m*6 + k], p.pose_W1[k*256 + n], a);
      su[ARu + m*264 + n] = f2b(gelu_f(a));
    }
    if (t < 256) su[ARu + 55*264 + t] = 0;
  }
  __syncthreads();
  {
    f32x4 e0[4] = {fz,fz,fz,fz}, e1[4] = {fz,fz,fz,fz};
    gemmE1(su, ARu, 264, p.wb + WP2, 2*wv, 2*wv+1, 16, e0, e1, lane);
    #pragma unroll
    for (int c = 0; c < 2; ++c){
      f32x4* ac = c ? e1 : e0;
      int colc = c ? col1 : col0;
      #pragma unroll
      for (int m = 0; m < 4; ++m){
        #pragma unroll
        for (int j = 0; j < 4; ++j){
          int row = m*16 + hi*4 + j;
          float v = 0.f;
          if (row < 56){
            v = (row < 55) ? (ac[m][j] + p.pose_b2[colc]) : p.transl_emb[colc];
            v = p.mask_ids[b*56 + row] ? v : p.mask_emb[colc];
            v += p.joints[row*256 + colc];
          }
          xsr[c][m][j] = v;
        }
      }
    }
  }
  __syncthreads();
  ln_regs(p.in_g, p.in_b, true);

  // ================= layers =================
  for (int l = 0; l < 4; ++l){
    const float* bqkv = p.sa_bqkv + l*768;

    for (int hp = 0; hp < 4; ++hp){
      su[VTo + (t>>8)*2304 + ((t>>3)&31)*72 + 56 + (t&7)] = 0;
      {
        int ctA = (wv < 4) ? 2*wv : wv + 4;
        int ctB = (wv < 4) ? 2*wv + 1 : ctA;
        f32x4 qA[4] = {fz,fz,fz,fz}, qB[4] = {fz,fz,fz,fz};
        gemmE1(su, XBb/2, 264, p.wb + WQKV + (size_t)(l*4 + hp)*49152, ctA, ctB, 12, qA, qB, lane);
        #pragma unroll
        for (int c = 0; c < 2; ++c){
          if (c == 1 && wv >= 4) break;
          f32x4* ac = c ? qB : qA;
          int ct = c ? ctB : ctA;
          int c192 = ct*16 + (lane & 15);
          int part = c192 >> 6, hh2 = (c192 >> 5) & 1, d = c192 & 31;
          float bias = bqkv[part*256 + (hp*2 + hh2)*32 + d];
          if (part == 0) bias *= 0.17677669529663687f;
          #pragma unroll
          for (int m = 0; m < 4; ++m){
            #pragma unroll
            for (int j = 0; j < 4; ++j){
              int row = m*16 + hi*4 + j;
              if (row < 56){
                float v = ac[m][j] + bias;
                if (part == 0)      su[QPo + hh2*2240 + row*40 + d] = f2b(v);
                else if (part == 1) su[KPo + hh2*2240 + row*40 + d] = f2b(v);
                else                su[VTo + hh2*2304 + d*72 + row] = f2b(v);
              }
            }
          }
        }
      }
      __syncthreads();

      for (int hh = 0; hh < 2; ++hh){
        {
          int m = wv >> 1;
          short8 a = *(const short8*)(su + QPo + hh*2240 + (m*16 + (lane&15))*40 + (hi<<3));
          #pragma unroll
          for (int i = 0; i < 2; ++i){
            int n = (wv & 1)*2 + i;
            short8 bf_ = *(const short8*)(su + KPo + hh*2240 + (n*16 + (lane&15))*40 + (hi<<3));
            f32x4 d = MFMA16(a, bf_, fz);
            #pragma unroll
            for (int j = 0; j < 4; ++j){
              int row = m*16 + hi*4 + j, key = n*16 + (lane & 15);
              if (row < 56 && key < 56)
                su[SCBo + row*72 + key] = f2b(d[j] + p.rel_map[row*56 + key]);
            }
          }
        }
        __syncthreads();
        #pragma unroll
        for (int q = 0; q < 7; ++q){
          int r = wv*7 + q;
          float v = (lane < 56) ? b2f(su[SCBo + r*72 + lane]) : -3.0e38f;
          float mx = wred_max(v);
          float ex = (lane < 56) ? __expf(v - mx) : 0.f;
          float s = wred_sum(ex);
          float a = ex / s;
          su[SCBo + r*72 + lane] = (lane < 56) ? f2b(a) : (unsigned short)0;
          if (l == 3) awr[q] += a * 0.125f;
        }
        __syncthreads();
        {
          int m = wv >> 1, dt = wv & 1;
          f32x4 o = fz;
          #pragma unroll
          for (int ks = 0; ks < 2; ++ks){
            short8 a  = *(const short8*)(su + SCBo + (m*16 + (lane&15))*72 + ks*32 + (hi<<3));
            short8 bf_= *(const short8*)(su + VTo + hh*2304 + (dt*16 + (lane&15))*72 + ks*32 + (hi<<3));
            o = MFMA16(a, bf_, o);
          }
          #pragma unroll
          for (int j = 0; j < 4; ++j){
            int row = m*16 + hi*4 + j;
            if (row < 56) su[OHo + row*40 + dt*16 + (lane & 15)] = f2b(o[j]);
          }
        }
        __syncthreads();
        {
          const unsigned short* Bg = p.wb + WO + (size_t)(l*8 + hp*2 + hh)*8192;
          short8 w0 = *(const short8*)(Bg + (size_t)(2*wv)*512 + lane*8);
          short8 w1 = *(const short8*)(Bg + (size_t)(2*wv+1)*512 + lane*8);
          #pragma unroll
          for (int m = 0; m < 4; ++m){
            short8 a = *(const short8*)(su + OHo + (m*16 + (lane&15))*40 + (hi<<3));
            xsr[0][m] = MFMA16(a, w0, xsr[0][m]);
            xsr[1][m] = MFMA16(a, w1, xsr[1][m]);
          }
        }
        __syncthreads();
      }
    } // head pairs

    {
      float bo0 = p.sa_bo[l*256 + col0], bo1 = p.sa_bo[l*256 + col1];
      #pragma unroll
      for (int m = 0; m < 4; ++m)
        #pragma unroll
        for (int j = 0; j < 4; ++j){ xsr[0][m][j] += bo0; xsr[1][m][j] += bo1; }
    }
    ln_regs(p.ln1_g + l*256, p.ln1_b + l*256, false);

    {
      int c = t & 255, pg = t >> 8;
      float a = 0.f;
      const float* W = p.ca_Wkv + (size_t)l*131072 + 256 + c;
      for (int k = pg*128; k < pg*128 + 128; ++k) a = fmaf(sf[CONDVf + k], W[(size_t)k*512], a);
      sf[PARTSGf + pg*256 + c] = a;
    }
    __syncthreads();
    if (t < 256) sf[VCSBf + t] = p.ca_bkv[l*512 + 256 + t] + sf[PARTSGf + t] + sf[PARTSGf + 256 + t];
    __syncthreads();
    {
      int c = t & 255, pg = t >> 8;
      float a = 0.f;
      const float* W = p.ca_Wo + (size_t)l*65536 + c;
      for (int k = pg*128; k < pg*128 + 128; ++k) a = fmaf(sf[VCSBf + k], W[(size_t)k*256], a);
      sf[PARTSGf + pg*256 + c] = a;
    }
    __syncthreads();
    if (t < 256) sf[OCVf + t] = p.ca_bo[l*256 + t] + sf[PARTSGf + t] + sf[PARTSGf + 256 + t];
    __syncthreads();
    {
      float o0 = sf[OCVf + col0], o1 = sf[OCVf + col1];
      #pragma unroll
      for (int m = 0; m < 4; ++m)
        #pragma unroll
        for (int j = 0; j < 4; ++j){ xsr[0][m][j] += o0; xsr[1][m][j] += o1; }
    }
    __syncthreads();
    ln_regs(p.ln2_g + l*256, p.ln2_b + l*256, true);

    for (int ch = 0; ch < 4; ++ch){
      f32x4 f0[4] = {fz,fz,fz,fz}, f1[4] = {fz,fz,fz,fz};
      gemmE1(su, XBb/2, 264, p.wb + WF1 + (size_t)(l*4 + ch)*65536, 2*wv, 2*wv+1, 16, f0, f1, lane);
      const float* b1 = p.ff_b1 + l*1024 + ch*256;
      #pragma unroll
      for (int c = 0; c < 2; ++c){
        f32x4* fc = c ? f1 : f0;
        int colc = c ? col1 : col0;
        #pragma unroll
        for (int m = 0; m < 4; ++m){
          #pragma unroll
          for (int j = 0; j < 4; ++j){
            int row = m*16 + hi*4 + j;
            if (row < 56) su[ARu + row*264 + colc] = f2b(gelu_f(fc[m][j] + b1[colc]));
          }
        }
      }
      __syncthreads();
      gemmE1(su, ARu, 264, p.wb + WF2 + (size_t)(l*4 + ch)*65536, 2*wv, 2*wv+1, 16, xsr[0], xsr[1], lane);
      __syncthreads();
    }
    {
      float bo0 = p.ff_b2[l*256 + col0], bo1 = p.ff_b2[l*256 + col1];
      #pragma unroll
      for (int m = 0; m < 4; ++m)
        #pragma unroll
        for (int j = 0; j < 4; ++j){ xsr[0][m][j] += bo0; xsr[1][m][j] += bo1; }
    }
    ln_regs(p.ln3_g + l*256, p.ln3_b + l*256, true);
  } // layers

  // ---- attn_w out ----
  if (lane < 56){
    #pragma unroll
    for (int q = 0; q < 7; ++q)
      p.out[OUT_AW + (size_t)b*3136 + (wv*7 + q)*56 + lane] = awr[q];
  }
  if (hi == 1){
    sf[X55f + col0] = xsr[0][3][3];
    sf[X55f + col1] = xsr[1][3][3];
  }

  // ---- pose head ----
  {
    float pacc = 0.f;
    int mp = t / 6, op = t - mp*6;
    for (int ch = 0; ch < 4; ++ch){
      f32x4 r0[4] = {fz,fz,fz,fz}, r1[4] = {fz,fz,fz,fz};
      gemmE1(su, XBb/2, 264, p.wb + WROT + (size_t)ch*65536, 2*wv, 2*wv+1, 16, r0, r1, lane);
      const float* rb = p.rot_b1 + ch*256;
      #pragma unroll
      for (int c = 0; c < 2; ++c){
        f32x4* rc = c ? r1 : r0;
        int colc = c ? col1 : col0;
        #pragma unroll
        for (int m = 0; m < 4; ++m){
          #pragma unroll
          for (int j = 0; j < 4; ++j){
            int row = m*16 + hi*4 + j;
            if (row < 56) su[ARu + row*264 + colc] = f2b(gelu_f(rc[m][j] + rb[colc]));
          }
        }
      }
      __syncthreads();
      if (t < 330){
        for (int d = 0; d < 256; ++d)
          pacc = fmaf(b2f(su[ARu + mp*264 + d]), p.rot_W2[(size_t)(ch*256 + d)*6 + op], pacc);
      }
      __syncthreads();
    }
    if (t < 330) p.out[(size_t)b*330 + t] = pacc + p.rot_b2[op];
  }

  // ---- transl head ----
  {
    #pragma unroll
    for (int hf = 0; hf < 2; ++hf){
      int c = t + hf*512;
      float a = p.tr_b1[c];
      for (int k = 0; k < 256; ++k) a = fmaf(sf[X55f + k], p.tr_W1[(size_t)k*1024 + c], a);
      sf[TRFf + c] = gelu_f(a);
    }
    __syncthreads();
    float part = 0.f;
    #pragma unroll
    for (int hf = 0; hf < 2; ++hf){
      int c = t + hf*512;
      part = fmaf(sf[TRFf + c], p.tr_W2[c], part);
    }
    part = wred_sum(part);
    if (lane == 0) sf[WSUMf + wv] = part;
    __syncthreads();
    if (t == 0){
      float s = p.tr_b2[0];
      #pragma unroll
      for (int w = 0; w < 8; ++w) s += sf[WSUMf + w];
      p.out[OUT_TR + b] = s;
    }
  }
}

extern "C" void kernel_launch(void* const* d_in, const int* in_sizes, int n_in,
                              void* d_out, int out_size, void* d_ws, size_t ws_size,
                              hipStream_t stream){
  (void)in_sizes; (void)n_in; (void)out_size; (void)ws_size;
  auto F = [&](int i) -> const float* { return (const float*)d_in[i]; };

  PP pp;
  pp.sa_Wqkv = F(20); pp.sa_Wo = F(22); pp.ff_W1 = F(30); pp.ff_W2 = F(32);
  pp.rot_W1 = F(40); pp.pose_W2 = F(5);
  pp.wb = (unsigned short*)d_ws;
  hipLaunchKernelGGL(prep_kernel, dim3((WTOT + 255u)/256u), dim3(256), 0, stream, pp);

  KP p;
  p.bp = F(0); p.wrist = F(1); p.betas = F(2);
  p.pose_W1 = F(3); p.pose_b1 = F(4); p.pose_b2 = F(6);
  p.joints = F(7); p.mask_emb = F(8); p.transl_emb = F(9);
  p.in_g = F(10); p.in_b = F(11);
  p.gender_tab = F(12);
  p.cond_W1 = F(13); p.cond_b1 = F(14); p.cond_W2 = F(15); p.cond_b2 = F(16);
  p.cond_g = F(17); p.cond_b = F(18);
  p.rel_map = F(19);
  p.sa_bqkv = F(21); p.sa_bo = F(23);
  p.ca_Wkv = F(26); p.ca_bkv = F(27); p.ca_Wo = F(28); p.ca_bo = F(29);
  p.ff_b1 = F(31); p.ff_b2 = F(33);
  p.ln1_g = F(34); p.ln1_b = F(35); p.ln2_g = F(36); p.ln2_b = F(37);
  p.ln3_g = F(38); p.ln3_b = F(39);
  p.rot_b1 = F(41); p.rot_W2 = F(42); p.rot_b2 = F(43);
  p.tr_W1 = F(44); p.tr_b1 = F(45); p.tr_W2 = F(46); p.tr_b2 = F(47);
  p.gender = (const int*)d_in[48]; p.mask_ids = (const int*)d_in[49];
  p.wb = (const unsigned short*)d_ws;
  p.out = (float*)d_out;

  hipLaunchKernelGGL(actor_kernel, dim3(NB), dim3(Tc), 0, stream, p);
}